// Round 1
// baseline (803.275 us; speedup 1.0000x reference)
//
#include <hip/hip_runtime.h>
#include <cstdint>
#include <cstddef>

// Problem constants (from reference): T=512, B=32, A=64, N=128, H=8
#define A_DIM 64
#define N_DIM 128
#define H_DIM 8
#define OUT_PER_BLK (A_DIM * (A_DIM - 1))   // 4032 floats
#define ATT_STRIDE 68                        // 64 + 4 pad: breaks LDS bank conflicts, keeps 16B align
#define TILES_PER_BLK 8                      // even; 16384 % 8 == 0 -> grid 2048

// Raw barrier: waits LDS ops only (producer->consumer via LDS), leaves global
// prefetch loads IN FLIGHT across the barrier (unlike __syncthreads, which
// drains vmcnt(0)). sched_barrier(0) pins post-barrier ds_reads below it.
__device__ __forceinline__ void sync_lds() {
    asm volatile("s_waitcnt lgkmcnt(0)" ::: "memory");
    __builtin_amdgcn_s_barrier();
    __builtin_amdgcn_sched_barrier(0);
}

// Static float4-element access (j compile-time after unroll -> folds to a reg)
#define SB_ELEM(b, j) (((j) & 3) == 0 ? (b)[(j) >> 2].x : \
                       ((j) & 3) == 1 ? (b)[(j) >> 2].y : \
                       ((j) & 3) == 2 ? (b)[(j) >> 2].z : (b)[(j) >> 2].w)

__device__ __forceinline__ void compute_tile(
    const float4 (&sb4)[8], int blk,
    int tid, int lane, int wv,
    const float* __restrict__ Wq, const float* __restrict__ bq,
    const float* __restrict__ Wk, const float* __restrict__ bk,
    float* __restrict__ out,
    float* smem, float* q_lds, float* k_lds)
{
    // ---------------- Phase 1: partial projections ----------------
    const int n0 = wv * 32;
    float qa[H_DIM] = {0,0,0,0,0,0,0,0};
    float ka[H_DIM] = {0,0,0,0,0,0,0,0};
    #pragma unroll
    for (int j = 0; j < 32; ++j) {
        const float s = SB_ELEM(sb4, j);
        const float* wqj = Wq + (n0 + j) * H_DIM;   // wave-uniform -> s_load
        const float* wkj = Wk + (n0 + j) * H_DIM;
        #pragma unroll
        for (int h = 0; h < H_DIM; ++h) {
            qa[h] = fmaf(s, wqj[h], qa[h]);
            ka[h] = fmaf(s, wkj[h], ka[h]);
        }
    }
    {
        float* p = smem + wv * (16 * 64) + lane;     // partial[w][g][i], conflict-free
        #pragma unroll
        for (int h = 0; h < H_DIM; ++h) {
            p[h * 64]       = qa[h];
            p[(8 + h) * 64] = ka[h];
        }
    }
    sync_lds();

    // ---------------- Phase 2: reduce over waves + bias ----------------
    {
        const int ii = tid >> 2;
        const int h2 = tid & 3;
        float v0 = 0.f, v1 = 0.f, v2 = 0.f, v3 = 0.f;
        #pragma unroll
        for (int w = 0; w < 4; ++w) {
            const float* p = smem + w * (16 * 64) + ii;
            v0 += p[(h2     ) * 64];
            v1 += p[(h2 +  4) * 64];
            v2 += p[(h2 +  8) * 64];
            v3 += p[(h2 + 12) * 64];
        }
        q_lds[ii * 8 + h2    ] = v0 + bq[h2];
        q_lds[ii * 8 + h2 + 4] = v1 + bq[h2 + 4];
        k_lds[ii * 8 + h2    ] = v2 + bk[h2];
        k_lds[ii * 8 + h2 + 4] = v3 + bk[h2 + 4];
    }
    sync_lds();

    // ---------------- Phase 3: att = Q @ K2 ----------------
    const int i  = tid >> 2;
    const int jb = tid & 3;
    float qv[H_DIM];
    #pragma unroll
    for (int h = 0; h < H_DIM; ++h) qv[h] = q_lds[i * 8 + h];

    float acc[16];
    #pragma unroll
    for (int c = 0; c < 16; ++c) acc[c] = 0.f;
    #pragma unroll
    for (int h = 0; h < H_DIM; ++h) {
        const float* kr = k_lds + h * 64 + jb * 16;  // K2[h][j] = k_flat[h*64+j]
        const float qh = qv[h];
        #pragma unroll
        for (int c = 0; c < 16; ++c) acc[c] = fmaf(qh, kr[c], acc[c]);
    }

    // ---------------- Phase 4: softmax over j (4 lanes per row) ----------------
    float m = acc[0];
    #pragma unroll
    for (int c = 1; c < 16; ++c) m = fmaxf(m, acc[c]);
    m = fmaxf(m, __shfl_xor(m, 1, 64));
    m = fmaxf(m, __shfl_xor(m, 2, 64));
    float ssum = 0.f;
    #pragma unroll
    for (int c = 0; c < 16; ++c) { acc[c] = __expf(acc[c] - m); ssum += acc[c]; }
    ssum += __shfl_xor(ssum, 1, 64);
    ssum += __shfl_xor(ssum, 2, 64);
    const float inv = 1.0f / ssum;

    {
        float* ar = smem + i * ATT_STRIDE + jb * 16;
        #pragma unroll
        for (int c = 0; c < 16; ++c) ar[c] = acc[c] * inv;
    }
    sync_lds();

    // ---------------- Phase 5: off-diagonal gather, coalesced float4 stores ----------------
    float4* out4 = (float4*)(out + (size_t)blk * OUT_PER_BLK);
    #pragma unroll
    for (int it = 0; it < 4; ++it) {
        const int o4 = it * 256 + tid;
        if (o4 < OUT_PER_BLK / 4) {
            float tmp[4];
            #pragma unroll
            for (int e = 0; e < 4; ++e) {
                const int idx = o4 * 4 + e;          // 0..4031
                const int ii  = idx / 63;            // magic-mul
                const int kk  = idx - ii * 63;
                const int jj  = kk + (kk >= ii ? 1 : 0);
                tmp[e] = smem[ii * ATT_STRIDE + jj];
            }
            out4[o4] = make_float4(tmp[0], tmp[1], tmp[2], tmp[3]);
        }
    }
    // protect smem (att) from the NEXT tile's phase-1 partial writes
    sync_lds();
}

// One block per 8 consecutive (t,b) tiles. 256 threads = 4 waves.
// 1-tile-deep register prefetch pipeline: next tile's loads stay in flight
// across all phase barriers (lgkmcnt-only barriers, no vmcnt drain).
__global__ __launch_bounds__(256, 3) void attn_kernel(
    const float* __restrict__ S,
    const float* __restrict__ Wq,
    const float* __restrict__ bq,
    const float* __restrict__ Wk,
    const float* __restrict__ bk,
    float* __restrict__ out)
{
    // smem: phase 1-2 partial[4][16][64] (16 KB), phase 4-5 att[64][68] (17 KB)
    __shared__ float smem[A_DIM * ATT_STRIDE];
    __shared__ float q_lds[A_DIM * H_DIM];
    __shared__ float k_lds[A_DIM * H_DIM];

    const int tid  = threadIdx.x;
    const int lane = tid & 63;
    const int wv   = __builtin_amdgcn_readfirstlane(tid >> 6);
    const int blk0 = blockIdx.x * TILES_PER_BLK;

    // this thread's slice base: row = lane, cols [wv*32, wv*32+32)
    const float* sbase = S + (size_t)blk0 * (A_DIM * N_DIM)
                           + (size_t)lane * N_DIM + (size_t)(wv * 32);

    float4 sbA[8], sbB[8];

    // prologue: load tile 0
    {
        const float4* sp = (const float4*)sbase;
        #pragma unroll
        for (int c = 0; c < 8; ++c) sbA[c] = sp[c];
    }

    #pragma unroll 1
    for (int t = 0; t < TILES_PER_BLK; t += 2) {
        // issue prefetch of tile t+1 (always valid: TILES_PER_BLK even)
        {
            const float4* sp = (const float4*)(sbase + (size_t)(t + 1) * (A_DIM * N_DIM));
            #pragma unroll
            for (int c = 0; c < 8; ++c) sbB[c] = sp[c];
        }
        compute_tile(sbA, blk0 + t, tid, lane, wv, Wq, bq, Wk, bk, out, smem, q_lds, k_lds);

        // issue prefetch of tile t+2 while computing t+1
        if (t + 2 < TILES_PER_BLK) {
            const float4* sp = (const float4*)(sbase + (size_t)(t + 2) * (A_DIM * N_DIM));
            #pragma unroll
            for (int c = 0; c < 8; ++c) sbA[c] = sp[c];
        }
        compute_tile(sbB, blk0 + t + 1, tid, lane, wv, Wq, bq, Wk, bk, out, smem, q_lds, k_lds);
    }
}

extern "C" void kernel_launch(void* const* d_in, const int* in_sizes, int n_in,
                              void* d_out, int out_size, void* d_ws, size_t ws_size,
                              hipStream_t stream) {
    const float* S  = (const float*)d_in[0];   // (T,B,A,N) fp32
    const float* Wq = (const float*)d_in[1];   // (N,H)
    const float* bq = (const float*)d_in[2];   // (H,)
    const float* Wk = (const float*)d_in[3];   // (N,H)
    const float* bk = (const float*)d_in[4];   // (H,)
    float* out = (float*)d_out;                // (T,B,A,A-1) fp32

    const int n_tiles  = in_sizes[0] / (A_DIM * N_DIM);  // T*B = 16384
    const int n_blocks = n_tiles / TILES_PER_BLK;        // 2048
    attn_kernel<<<dim3(n_blocks), dim3(256), 0, stream>>>(S, Wq, bq, Wk, bk, out);
}